// Round 2
// baseline (4837.350 us; speedup 1.0000x reference)
//
#include <hip/hip_runtime.h>
#include <cstdint>
#include <cstddef>

typedef short bf16x8 __attribute__((ext_vector_type(8)));
typedef float f32x4 __attribute__((ext_vector_type(4)));

#define DEV static __device__ __forceinline__

DEV unsigned short f2bf(float x){
  union{float f; unsigned int u;} v; v.f = x;
  unsigned int r = (v.u + 0x7FFFu + ((v.u>>16)&1u)) >> 16;
  return (unsigned short)r;
}
DEV float bf2f(unsigned short h){
  union{unsigned int u; float f;} v; v.u = ((unsigned int)h)<<16;
  return v.f;
}
DEV float sigm(float x){ return 1.0f/(1.0f + __expf(-x)); }

// ---------------- prep kernels ----------------
__global__ void k_f2bf(const float* __restrict__ src, unsigned short* __restrict__ dst, int n){
  int i = blockIdx.x*256 + threadIdx.x;
  if(i<n) dst[i] = f2bf(src[i]);
}

__global__ void k_transpose(const float* __restrict__ in, float* __restrict__ out, int R, int C){
  int i = blockIdx.x*256 + threadIdx.x;
  if(i < R*C){ int r = i/C, c = i - r*C; out[(size_t)c*R + r] = in[i]; }
}

__global__ void k_attw1(const float* __restrict__ w1, unsigned short* __restrict__ dst){
  int i = blockIdx.x*256 + threadIdx.x;  // 128*1824
  if(i < 128*1824){
    int r = i/1824, cc = i - r*1824;
    float v = (r<100 && cc<1794)? w1[r*1794 + cc] : 0.0f;
    dst[i] = f2bf(v);
  }
}

__global__ void k_attwT(const float* __restrict__ aw, unsigned short* __restrict__ dst){
  int i = blockIdx.x*256 + threadIdx.x;  // out[n*256+k] = aw[k*256+n]
  if(i<65536){ int n = i>>8, k = i&255; dst[i] = f2bf(aw[k*256 + n]); }
}

__global__ void k_b1pad(const float* __restrict__ b1, float* __restrict__ dst){
  int i = threadIdx.x; if(i<128) dst[i] = (i<100)? b1[i] : 0.0f;
}

__global__ void k_copy(const float* __restrict__ s, float* __restrict__ d, int n){
  int i = blockIdx.x*256+threadIdx.x; if(i<n) d[i]=s[i];
}

// ---------------- generic bf16 MFMA GEMM: C(M,N) = A(M,K) @ Bt(N,K)^T ----------------
// block 256 (4 waves), 64x64 tile, each wave a 32x32 quadrant. M,N multiples of 64, K of 32.
__global__ __launch_bounds__(256) void k_gemm_bf16(
    const unsigned short* __restrict__ A, const unsigned short* __restrict__ Bt,
    int K, const float* __restrict__ bias, int act,
    float* __restrict__ outf, unsigned short* __restrict__ outbf, int ldc)
{
  int lane = threadIdx.x & 63, wave = threadIdx.x >> 6;
  int m_base = blockIdx.x*64 + (wave>>1)*32;
  int n_base = blockIdx.y*64 + (wave&1)*32;
  int cl = lane & 15, q4 = lane >> 4;
  f32x4 acc00={0.f,0.f,0.f,0.f}, acc01=acc00, acc10=acc00, acc11=acc00;
  const int kf_n = K >> 5;
  for(int kf=0; kf<kf_n; kf++){
    int ko = kf*32 + q4*8;
    bf16x8 a0 = *(const bf16x8*)(A + (size_t)(m_base+cl)*K + ko);
    bf16x8 a1 = *(const bf16x8*)(A + (size_t)(m_base+16+cl)*K + ko);
    bf16x8 b0 = *(const bf16x8*)(Bt + (size_t)(n_base+cl)*K + ko);
    bf16x8 b1 = *(const bf16x8*)(Bt + (size_t)(n_base+16+cl)*K + ko);
    acc00 = __builtin_amdgcn_mfma_f32_16x16x32_bf16(a0,b0,acc00,0,0,0);
    acc01 = __builtin_amdgcn_mfma_f32_16x16x32_bf16(a0,b1,acc01,0,0,0);
    acc10 = __builtin_amdgcn_mfma_f32_16x16x32_bf16(a1,b0,acc10,0,0,0);
    acc11 = __builtin_amdgcn_mfma_f32_16x16x32_bf16(a1,b1,acc11,0,0,0);
  }
  #pragma unroll
  for(int mt=0; mt<2; mt++){
    #pragma unroll
    for(int nt=0; nt<2; nt++){
      f32x4 av = (mt==0)? (nt==0?acc00:acc01) : (nt==0?acc10:acc11);
      int col = n_base + nt*16 + cl;
      float bv = bias? bias[col] : 0.0f;
      #pragma unroll
      for(int r=0;r<4;r++){
        int row = m_base + mt*16 + q4*4 + r;
        float v = av[r] + bv;
        if(act) v = tanhf(v);
        if(outbf) outbf[(size_t)row*ldc + col] = f2bf(v);
        else      outf [(size_t)row*ldc + col] = v;
      }
    }
  }
}

// ---------------- GRU recurrence: 4 blocks (2 context M=16, 2 query M=16) ----------------
// W (768x256 bf16) register-resident per wave; gates via LDS; gi prefetched bf16.
// __launch_bounds__(512,1): 8-wave block => HW cap 256 VGPR; declaring min 1 wave/EU
// stops the compiler from capping at 128 and spilling the 192-VGPR weight array
// (round 1: VGPR_Count=128 -> massive scratch traffic, 9050 cyc/step).
__global__ __launch_bounds__(512,1) void k_gru_rec(
    const unsigned short* __restrict__ whh_c, const unsigned short* __restrict__ whh_q,
    const unsigned short* __restrict__ gi_c,  const unsigned short* __restrict__ gi_q,
    const float* __restrict__ bhh_c, const float* __restrict__ bhh_q,
    const float* __restrict__ h0_c,  const float* __restrict__ h0_q,
    float* __restrict__ c_out, float* __restrict__ q_hT)
{
  __shared__ unsigned short h_bf[16*264];   // padded rows: stride 264 bf16 (528B)
  __shared__ float g_s[16*772];             // raw gate GEMM result, padded stride
  __shared__ float bhh_s[768];

  const int blk = blockIdx.x;
  const bool isq = blk >= 2;
  const int b0 = (isq? blk-2 : blk) * 16;
  const unsigned short* W  = isq? whh_q : whh_c;
  const unsigned short* GI = isq? gi_q  : gi_c;
  const float* bhh = isq? bhh_q : bhh_c;
  const float* h0  = isq? h0_q  : h0_c;
  const int steps  = isq? 32 : 1024;

  const int tid = threadIdx.x;
  const int lane = tid & 63, wave = tid >> 6;
  const int cl = lane & 15, q4 = lane >> 4;

  // B-fragments: wave owns 6 N-tiles x 8 K-frags (192 VGPRs)
  bf16x8 Bf[6][8];
  #pragma unroll
  for(int nt=0; nt<6; nt++){
    const unsigned short* wrow = W + (size_t)((wave*6+nt)*16 + cl)*256;
    #pragma unroll
    for(int kf=0; kf<8; kf++)
      Bf[nt][kf] = *(const bf16x8*)(wrow + kf*32 + q4*8);
  }
  for(int i=tid; i<768; i+=512) bhh_s[i] = bhh[i];

  const int m  = tid >> 5;        // 0..15 (phase-B row)
  const int j0 = (tid & 31) * 8;  // 0..248 (phase-B hidden chunk)
  {
    bf16x8 hv;
    #pragma unroll
    for(int i=0;i<8;i++) hv[i] = (short)f2bf(h0[(size_t)(b0+m)*256 + j0 + i]);
    *(bf16x8*)&h_bf[m*264 + j0] = hv;
  }
  __syncthreads();

  for(int t=0; t<steps; t++){
    // prefetch gi (bf16) for this step; consumed after barrier -> latency hides under MFMA
    const unsigned short* gp = GI + ((size_t)(b0+m)*steps + t)*768 + j0;
    bf16x8 gi_r = *(const bf16x8*)(gp);
    bf16x8 gi_z = *(const bf16x8*)(gp + 256);
    bf16x8 gi_n = *(const bf16x8*)(gp + 512);

    // phase A: g = h @ W^T  (48 MFMAs/wave)
    f32x4 acc[6];
    #pragma unroll
    for(int nt=0;nt<6;nt++){ f32x4 z = {0.f,0.f,0.f,0.f}; acc[nt] = z; }
    #pragma unroll
    for(int kf=0; kf<8; kf++){
      bf16x8 a = *(const bf16x8*)&h_bf[cl*264 + kf*32 + q4*8];
      #pragma unroll
      for(int nt=0; nt<6; nt++)
        acc[nt] = __builtin_amdgcn_mfma_f32_16x16x32_bf16(a, Bf[nt][kf], acc[nt], 0,0,0);
    }
    #pragma unroll
    for(int nt=0; nt<6; nt++){
      int n0 = (wave*6+nt)*16 + cl;
      #pragma unroll
      for(int r=0;r<4;r++) g_s[(q4*4+r)*772 + n0] = acc[nt][r];
    }
    __syncthreads();

    // phase B: GRU elementwise update (fp32)
    const float* grow = &g_s[m*772];
    bf16x8 hold8 = *(const bf16x8*)&h_bf[m*264 + j0];
    f32x4 hnv[2];
    bf16x8 hv;
    #pragma unroll
    for(int half=0; half<2; half++){
      const int jh = j0 + half*4;
      f32x4 gA = *(const f32x4*)&grow[jh];
      f32x4 gB = *(const f32x4*)&grow[256+jh];
      f32x4 gC = *(const f32x4*)&grow[512+jh];
      f32x4 bA = *(const f32x4*)&bhh_s[jh];
      f32x4 bB = *(const f32x4*)&bhh_s[256+jh];
      f32x4 bC = *(const f32x4*)&bhh_s[512+jh];
      #pragma unroll
      for(int i=0;i<4;i++){
        const int ii = half*4+i;
        float rr = sigm(bf2f((unsigned short)gi_r[ii]) + gA[i] + bA[i]);
        float zz = sigm(bf2f((unsigned short)gi_z[ii]) + gB[i] + bB[i]);
        float nn = tanhf(bf2f((unsigned short)gi_n[ii]) + rr*(gC[i] + bC[i]));
        float ho = bf2f((unsigned short)hold8[ii]);
        float x = (1.0f - zz)*nn + zz*ho;
        hnv[half][i] = x;
        hv[ii] = (short)f2bf(x);
      }
    }
    *(bf16x8*)&h_bf[m*264 + j0] = hv;
    if(!isq){
      float* crow = c_out + ((size_t)(b0+m)*1024 + t)*256 + j0;
      *(f32x4*)&crow[0] = hnv[0];
      *(f32x4*)&crow[4] = hnv[1];
    } else if(t == steps-1){
      float* qrow = q_hT + (size_t)(b0+m)*256 + j0;
      *(f32x4*)&qrow[0] = hnv[0];
      *(f32x4*)&qrow[4] = hnv[1];
    }
    __syncthreads();
  }
}

// ---------------- attention helpers ----------------
__global__ void k_gather(const float* __restrict__ c_out, const int* __restrict__ c_index,
                         float* __restrict__ c_sel, unsigned short* __restrict__ c_sel_bf){
  int row = blockIdx.x;                 // 0..4095 = b*128+s
  int b = row >> 7, s = row & 127;
  int idx = c_index[b*128 + s];
  float v = c_out[((size_t)b*1024 + idx)*256 + threadIdx.x];
  c_sel   [(size_t)row*256 + threadIdx.x] = v;
  c_sel_bf[(size_t)row*256 + threadIdx.x] = f2bf(v);
}

__global__ void k_feats(const float* __restrict__ c_sel, const float* __restrict__ cw,
                        const float* __restrict__ m_, const float* __restrict__ qh,
                        unsigned short* __restrict__ feats){
  int row = blockIdx.x, tid = threadIdx.x;
  int b = row >> 7;
  float cs  = c_sel[(size_t)row*256 + tid];
  float mj  = m_[b*256 + tid];
  float qj  = qh[b*256 + tid];
  float cwj = cw[(size_t)row*256 + tid];
  float dq = cwj*qj, dm = cwj*mj;
  #pragma unroll
  for(int o=32;o>0;o>>=1){ dq += __shfl_down(dq,o); dm += __shfl_down(dm,o); }
  __shared__ float rq[4], rm[4];
  int lane = tid&63, wave=tid>>6;
  if(lane==0){ rq[wave]=dq; rm[wave]=dm; }
  __syncthreads();
  unsigned short* fr = feats + (size_t)row*1824;
  fr[tid]      = f2bf(cs);
  fr[256+tid]  = f2bf(mj);
  fr[512+tid]  = f2bf(qj);
  fr[768+tid]  = f2bf(cs*qj);
  fr[1024+tid] = f2bf(cs*mj);
  fr[1280+tid] = f2bf(fabsf(cs-qj));
  fr[1536+tid] = f2bf(fabsf(cs-mj));
  if(tid==0){
    float DQ = rq[0]+rq[1]+rq[2]+rq[3];
    float DM = rm[0]+rm[1]+rm[2]+rm[3];
    fr[1792]=f2bf(DQ); fr[1793]=f2bf(DM);
  }
  if(tid<30) fr[1794+tid]=0;   // zero K-pad
}

__global__ void k_scores(const float* __restrict__ h1, const float* __restrict__ w2,
                         const float* __restrict__ b2, float* __restrict__ scores){
  int row = blockIdx.x*4 + (threadIdx.x>>6);
  int lane = threadIdx.x & 63;
  float v = 0.0f;
  if(lane < 100)    v += h1[(size_t)row*128 + lane]*w2[lane];
  if(lane+64 < 100) v += h1[(size_t)row*128 + lane+64]*w2[lane+64];
  #pragma unroll
  for(int o=32;o>0;o>>=1) v += __shfl_down(v,o);
  if(lane==0) scores[row] = v + b2[0];
}

__global__ void k_softmax_e(const float* __restrict__ scores, const int* __restrict__ len_c,
                            const float* __restrict__ c_sel, float* __restrict__ out_att,
                            float* __restrict__ e){
  __shared__ float red[256];
  __shared__ float p[128];
  int b = blockIdx.x, tid = threadIdx.x;
  int L = len_c[b];
  float s = -1e30f;
  if(tid<128 && tid<L) s = scores[b*128+tid];
  red[tid]=s; __syncthreads();
  for(int o=128;o>0;o>>=1){ if(tid<o) red[tid]=fmaxf(red[tid],red[tid+o]); __syncthreads(); }
  float mx = red[0]; __syncthreads();
  float ex = (tid<128 && tid<L)? __expf(s-mx) : 0.0f;
  red[tid]=ex; __syncthreads();
  for(int o=128;o>0;o>>=1){ if(tid<o) red[tid]+=red[tid+o]; __syncthreads(); }
  float inv = 1.0f/red[0];
  if(tid<128){ float pv = ex*inv; p[tid]=pv; out_att[b*128+tid]=pv; }
  __syncthreads();
  float acc = 0.0f;
  for(int si=0; si<128; si++) acc += p[si]*c_sel[((size_t)b*128+si)*256 + tid];
  e[b*256+tid] = acc;
}

// ---------------- small fp32 GRU cell (mem/ans updates), x = [x1 || x2] ----------------
__global__ void k_gru_cell(const float* __restrict__ x1, int len1,
                           const float* __restrict__ x2, int len2,
                           const float* __restrict__ hprev,
                           const float* __restrict__ wihT, const float* __restrict__ whhT,
                           const float* __restrict__ bih, const float* __restrict__ bhh,
                           float* __restrict__ hout){
  __shared__ float xs[2304];
  __shared__ float hs[256];
  int m = blockIdx.x, tid = threadIdx.x;
  int Kx = len1 + len2;
  for(int i=tid;i<len1;i+=256) xs[i] = x1[(size_t)m*len1 + i];
  for(int i=tid;i<len2;i+=256) xs[len1+i] = x2[(size_t)m*len2 + i];
  hs[tid] = hprev[m*256 + tid];
  __syncthreads();
  float ar=0, az=0, an=0;
  for(int k=0;k<Kx;k++){
    float xv = xs[k];
    const float* wr = wihT + (size_t)k*768;
    ar += xv*wr[tid]; az += xv*wr[256+tid]; an += xv*wr[512+tid];
  }
  float gr=0, gz=0, gn=0;
  for(int k=0;k<256;k++){
    float hv = hs[k];
    const float* wr = whhT + (size_t)k*768;
    gr += hv*wr[tid]; gz += hv*wr[256+tid]; gn += hv*wr[512+tid];
  }
  float rr = sigm(ar + bih[tid]     + gr + bhh[tid]);
  float zz = sigm(az + bih[256+tid] + gz + bhh[256+tid]);
  float nn = tanhf(an + bih[512+tid] + rr*(gn + bhh[512+tid]));
  hout[m*256+tid] = (1.0f-zz)*nn + zz*hs[tid];
}

// ---------------- answer head ----------------
__global__ void k_logits(const float* __restrict__ msq, const float* __restrict__ out_wT,
                         const float* __restrict__ out_b, float* __restrict__ ylin){
  int i = blockIdx.x*256 + threadIdx.x;
  if(i >= 32*2000) return;
  int mrow = i/2000, n = i - mrow*2000;
  float acc = out_b[n];
  const float* mr = msq + mrow*256;
  for(int k=0;k<256;k++) acc += mr[k]*out_wT[(size_t)k*2000 + n];
  ylin[i] = acc;
}

__global__ void k_softmax_o(const float* __restrict__ x, float* __restrict__ y){
  __shared__ float red[256];
  int b = blockIdx.x, tid = threadIdx.x;
  const float* xr = x + (size_t)b*2000;
  float mx = -1e30f;
  for(int i=tid;i<2000;i+=256) mx = fmaxf(mx, xr[i]);
  red[tid]=mx; __syncthreads();
  for(int o=128;o>0;o>>=1){ if(tid<o) red[tid]=fmaxf(red[tid],red[tid+o]); __syncthreads(); }
  mx = red[0]; __syncthreads();
  float sum=0.0f;
  for(int i=tid;i<2000;i+=256) sum += __expf(xr[i]-mx);
  red[tid]=sum; __syncthreads();
  for(int o=128;o>0;o>>=1){ if(tid<o) red[tid]+=red[tid+o]; __syncthreads(); }
  float inv = 1.0f/red[0];
  for(int i=tid;i<2000;i+=256) y[(size_t)b*2000+i] = __expf(xr[i]-mx)*inv;
}

// ---------------- launch ----------------
extern "C" void kernel_launch(void* const* d_in, const int* in_sizes, int n_in,
                              void* d_out, int out_size, void* d_ws, size_t ws_size,
                              hipStream_t stream)
{
  const float* c        = (const float*)d_in[0];
  const float* q        = (const float*)d_in[1];
  const float* i_state  = (const float*)d_in[2];
  const float* q_state  = (const float*)d_in[3];
  const float* in_w_ih  = (const float*)d_in[4];
  const float* in_w_hh  = (const float*)d_in[5];
  const float* in_b_ih  = (const float*)d_in[6];
  const float* in_b_hh  = (const float*)d_in[7];
  const float* qe_w_ih  = (const float*)d_in[8];
  const float* qe_w_hh  = (const float*)d_in[9];
  const float* qe_b_ih  = (const float*)d_in[10];
  const float* qe_b_hh  = (const float*)d_in[11];
  const float* att_weight = (const float*)d_in[12];
  const float* att_w1   = (const float*)d_in[13];
  const float* att_b1   = (const float*)d_in[14];
  const float* att_w2   = (const float*)d_in[15];
  const float* att_b2   = (const float*)d_in[16];
  const float* mem_w_ih = (const float*)d_in[17];
  const float* mem_w_hh = (const float*)d_in[18];
  const float* mem_b_ih = (const float*)d_in[19];
  const float* mem_b_hh = (const float*)d_in[20];
  const float* out_w    = (const float*)d_in[21];
  const float* out_b    = (const float*)d_in[22];
  const float* ans_w_ih = (const float*)d_in[23];
  const float* ans_w_hh = (const float*)d_in[24];
  const float* ans_b_ih = (const float*)d_in[25];
  const float* ans_b_hh = (const float*)d_in[26];
  const int*   c_index  = (const int*)d_in[27];
  const int*   len_c    = (const int*)d_in[28];
  float* outp = (float*)d_out;   // [0,64000) y ; [64000,76288) att (3,32,128)

  char* wp = (char*)d_ws;
  auto take = [&](size_t nbytes)->char*{
    char* p = wp; wp += (nbytes + 255) & ~(size_t)255; return p;
  };
  unsigned short* c_bf      = (unsigned short*)take((size_t)32*1024*128*2);
  unsigned short* q_bf      = (unsigned short*)take((size_t)32*32*128*2);
  unsigned short* wih_in_bf = (unsigned short*)take(768*128*2);
  unsigned short* wih_qe_bf = (unsigned short*)take(768*128*2);
  unsigned short* whh_in_bf = (unsigned short*)take(768*256*2);
  unsigned short* whh_qe_bf = (unsigned short*)take(768*256*2);
  unsigned short* attwT_bf  = (unsigned short*)take(256*256*2);
  unsigned short* attw1_bf  = (unsigned short*)take(128*1824*2);
  float* b1pad              = (float*)take(128*4);
  float* out_wT             = (float*)take((size_t)256*2000*4);
  float* mem_wihT           = (float*)take(256*768*4);
  float* mem_whhT           = (float*)take(256*768*4);
  float* ans_wihT           = (float*)take((size_t)2256*768*4);
  float* ans_whhT           = (float*)take(256*768*4);
  unsigned short* gi_c_bf   = (unsigned short*)take((size_t)32768*768*2);
  unsigned short* gi_q_bf   = (unsigned short*)take((size_t)1024*768*2);
  float* c_out              = (float*)take((size_t)32*1024*256*4);
  float* q_hT               = (float*)take(32*256*4);
  float* c_sel              = (float*)take((size_t)4096*256*4);
  unsigned short* c_sel_bf  = (unsigned short*)take((size_t)4096*256*2);
  float* cw                 = (float*)take((size_t)4096*256*4);
  unsigned short* feats_bf  = (unsigned short*)take((size_t)4096*1824*2);
  float* h1                 = (float*)take((size_t)4096*128*4);
  float* scores             = (float*)take(4096*4);
  float* e_buf              = (float*)take(32*256*4);
  float* m_buf              = (float*)take(32*256*4);
  float* msq                = (float*)take(32*256*4);
  float* ylin               = (float*)take((size_t)32*2000*4);
  float* ybuf               = (float*)take((size_t)32*2000*4);

  // ---- prep / conversions ----
  k_f2bf<<<16384,256,0,stream>>>(c, c_bf, 32*1024*128);
  k_f2bf<<<512,256,0,stream>>>(q, q_bf, 32*32*128);
  k_f2bf<<<384,256,0,stream>>>(in_w_ih, wih_in_bf, 768*128);
  k_f2bf<<<384,256,0,stream>>>(qe_w_ih, wih_qe_bf, 768*128);
  k_f2bf<<<768,256,0,stream>>>(in_w_hh, whh_in_bf, 768*256);
  k_f2bf<<<768,256,0,stream>>>(qe_w_hh, whh_qe_bf, 768*256);
  k_attwT<<<256,256,0,stream>>>(att_weight, attwT_bf);
  k_attw1<<<912,256,0,stream>>>(att_w1, attw1_bf);
  k_b1pad<<<1,128,0,stream>>>(att_b1, b1pad);
  k_transpose<<<2000,256,0,stream>>>(out_w, out_wT, 2000, 256);
  k_transpose<<<768,256,0,stream>>>(mem_w_ih, mem_wihT, 768, 256);
  k_transpose<<<768,256,0,stream>>>(mem_w_hh, mem_whhT, 768, 256);
  k_transpose<<<6768,256,0,stream>>>(ans_w_ih, ans_wihT, 768, 2256);
  k_transpose<<<768,256,0,stream>>>(ans_w_hh, ans_whhT, 768, 256);

  // ---- time-parallel input projections: gi = x @ w_ih^T + b_ih  (bf16 out) ----
  k_gemm_bf16<<<dim3(512,12),256,0,stream>>>(c_bf, wih_in_bf, 128, in_b_ih, 0, nullptr, gi_c_bf, 768);
  k_gemm_bf16<<<dim3(16,12),256,0,stream>>>(q_bf, wih_qe_bf, 128, qe_b_ih, 0, nullptr, gi_q_bf, 768);

  // ---- sequential GRU recurrences (context 1024 steps + query 32 steps) ----
  k_gru_rec<<<4,512,0,stream>>>(whh_in_bf, whh_qe_bf, gi_c_bf, gi_q_bf,
                                in_b_hh, qe_b_hh, i_state, q_state, c_out, q_hT);

  // ---- attention setup ----
  k_gather<<<4096,256,0,stream>>>(c_out, c_index, c_sel, c_sel_bf);
  k_gemm_bf16<<<dim3(64,4),256,0,stream>>>(c_sel_bf, attwT_bf, 256, nullptr, 0, cw, nullptr, 256);
  k_copy<<<32,256,0,stream>>>(q_hT, m_buf, 32*256);

  // ---- 3 episodic memory iterations ----
  for(int it=0; it<3; it++){
    k_feats<<<4096,256,0,stream>>>(c_sel, cw, m_buf, q_hT, feats_bf);
    k_gemm_bf16<<<dim3(64,2),256,0,stream>>>(feats_bf, attw1_bf, 1824, b1pad, 1, h1, nullptr, 128);
    k_scores<<<1024,256,0,stream>>>(h1, att_w2, att_b2, scores);
    k_softmax_e<<<32,256,0,stream>>>(scores, len_c, c_sel, outp + 64000 + it*4096, e_buf);
    k_gru_cell<<<32,256,0,stream>>>(e_buf, 256, nullptr, 0, m_buf,
                                    mem_wihT, mem_whhT, mem_b_ih, mem_b_hh, m_buf);
  }

  // ---- answer module ----
  k_copy<<<32,256,0,stream>>>(m_buf, msq, 32*256);
  for(int it=0; it<2; it++){
    k_logits<<<250,256,0,stream>>>(msq, out_wT, out_b, ylin);
    k_softmax_o<<<32,256,0,stream>>>(ylin, ybuf);
    k_gru_cell<<<32,256,0,stream>>>(ybuf, 2000, q_hT, 256, msq,
                                    ans_wihT, ans_whhT, ans_b_ih, ans_b_hh, msq);
  }
  k_logits<<<250,256,0,stream>>>(msq, out_wT, out_b, ylin);
  k_softmax_o<<<32,256,0,stream>>>(ylin, outp);
}

// Round 3
// 3483.229 us; speedup vs baseline: 1.3888x; 1.3888x over previous
//
#include <hip/hip_runtime.h>
#include <cstdint>
#include <cstddef>

typedef short bf16x8 __attribute__((ext_vector_type(8)));
typedef float f32x4 __attribute__((ext_vector_type(4)));

#define DEV static __device__ __forceinline__

DEV unsigned short f2bf(float x){
  union{float f; unsigned int u;} v; v.f = x;
  unsigned int r = (v.u + 0x7FFFu + ((v.u>>16)&1u)) >> 16;
  return (unsigned short)r;
}
DEV float bf2f(unsigned short h){
  union{unsigned int u; float f;} v; v.u = ((unsigned int)h)<<16;
  return v.f;
}
// fast gates: v_exp_f32 + v_rcp_f32 (~1e-7 rel err, fine vs bf16-scale threshold)
DEV float sigm_f(float x){ return __builtin_amdgcn_rcpf(1.0f + __expf(-x)); }
DEV float tanh_f(float x){ return 2.0f*__builtin_amdgcn_rcpf(1.0f + __expf(-2.0f*x)) - 1.0f; }

DEV void glds16(const void* gsrc, void* lds_dst){
  __builtin_amdgcn_global_load_lds(
    (const __attribute__((address_space(1))) unsigned int*)gsrc,
    (__attribute__((address_space(3))) unsigned int*)lds_dst, 16, 0, 0);
}

// ---------------- prep kernels ----------------
__global__ void k_f2bf(const float* __restrict__ src, unsigned short* __restrict__ dst, int n){
  int i = blockIdx.x*256 + threadIdx.x;
  if(i<n) dst[i] = f2bf(src[i]);
}

__global__ void k_transpose(const float* __restrict__ in, float* __restrict__ out, int R, int C){
  int i = blockIdx.x*256 + threadIdx.x;
  if(i < R*C){ int r = i/C, c = i - r*C; out[(size_t)c*R + r] = in[i]; }
}

__global__ void k_attw1(const float* __restrict__ w1, unsigned short* __restrict__ dst){
  int i = blockIdx.x*256 + threadIdx.x;  // 128*1824
  if(i < 128*1824){
    int r = i/1824, cc = i - r*1824;
    float v = (r<100 && cc<1794)? w1[r*1794 + cc] : 0.0f;
    dst[i] = f2bf(v);
  }
}

__global__ void k_attwT(const float* __restrict__ aw, unsigned short* __restrict__ dst){
  int i = blockIdx.x*256 + threadIdx.x;  // out[n*256+k] = aw[k*256+n]
  if(i<65536){ int n = i>>8, k = i&255; dst[i] = f2bf(aw[k*256 + n]); }
}

__global__ void k_b1pad(const float* __restrict__ b1, float* __restrict__ dst){
  int i = threadIdx.x; if(i<128) dst[i] = (i<100)? b1[i] : 0.0f;
}

__global__ void k_copy(const float* __restrict__ s, float* __restrict__ d, int n){
  int i = blockIdx.x*256+threadIdx.x; if(i<n) d[i]=s[i];
}

// ---------------- generic bf16 MFMA GEMM: C(M,N) = A(M,K) @ Bt(N,K)^T ----------------
__global__ __launch_bounds__(256) void k_gemm_bf16(
    const unsigned short* __restrict__ A, const unsigned short* __restrict__ Bt,
    int K, const float* __restrict__ bias, int act,
    float* __restrict__ outf, unsigned short* __restrict__ outbf, int ldc)
{
  int lane = threadIdx.x & 63, wave = threadIdx.x >> 6;
  int m_base = blockIdx.x*64 + (wave>>1)*32;
  int n_base = blockIdx.y*64 + (wave&1)*32;
  int cl = lane & 15, q4 = lane >> 4;
  f32x4 acc00={0.f,0.f,0.f,0.f}, acc01=acc00, acc10=acc00, acc11=acc00;
  const int kf_n = K >> 5;
  for(int kf=0; kf<kf_n; kf++){
    int ko = kf*32 + q4*8;
    bf16x8 a0 = *(const bf16x8*)(A + (size_t)(m_base+cl)*K + ko);
    bf16x8 a1 = *(const bf16x8*)(A + (size_t)(m_base+16+cl)*K + ko);
    bf16x8 b0 = *(const bf16x8*)(Bt + (size_t)(n_base+cl)*K + ko);
    bf16x8 b1 = *(const bf16x8*)(Bt + (size_t)(n_base+16+cl)*K + ko);
    acc00 = __builtin_amdgcn_mfma_f32_16x16x32_bf16(a0,b0,acc00,0,0,0);
    acc01 = __builtin_amdgcn_mfma_f32_16x16x32_bf16(a0,b1,acc01,0,0,0);
    acc10 = __builtin_amdgcn_mfma_f32_16x16x32_bf16(a1,b0,acc10,0,0,0);
    acc11 = __builtin_amdgcn_mfma_f32_16x16x32_bf16(a1,b1,acc11,0,0,0);
  }
  #pragma unroll
  for(int mt=0; mt<2; mt++){
    #pragma unroll
    for(int nt=0; nt<2; nt++){
      f32x4 av = (mt==0)? (nt==0?acc00:acc01) : (nt==0?acc10:acc11);
      int col = n_base + nt*16 + cl;
      float bv = bias? bias[col] : 0.0f;
      #pragma unroll
      for(int r=0;r<4;r++){
        int row = m_base + mt*16 + q4*4 + r;
        float v = av[r] + bv;
        if(act) v = tanh_f(v);
        if(outbf) outbf[(size_t)row*ldc + col] = f2bf(v);
        else      outf [(size_t)row*ldc + col] = v;
      }
    }
  }
}

// ---------------- GRU recurrence ----------------
// 4 blocks (2 context, 2 query), 16 batch rows each, 8 waves.
// Gate-local tiling: wave w owns cols [32w,32w+32) of each gate r/z/n ->
// GRU update runs in-register on the MFMA accumulators (no gate LDS round-trip).
// h carried in registers (hreg) per owning lane; LDS h_bf only feeds A-frags.
// gi staged via global_load_lds (no VGPR round-trip). W register-resident (192 VGPR).
__global__ __launch_bounds__(512,1) void k_gru_rec(
    const unsigned short* __restrict__ whh_c, const unsigned short* __restrict__ whh_q,
    const unsigned short* __restrict__ gi_c,  const unsigned short* __restrict__ gi_q,
    const float* __restrict__ bhh_c, const float* __restrict__ bhh_q,
    const float* __restrict__ h0_c,  const float* __restrict__ h0_q,
    float* __restrict__ c_out, float* __restrict__ q_hT)
{
  __shared__ unsigned short h_bf[16*264];    // row stride 264 u16 (132 dw)
  __shared__ unsigned short gi_s[16*1032];   // row stride 1032 u16 = 2064 B (16B-aligned; pad [768,1032) absorbs glds overrun)

  const int blk = blockIdx.x;
  const bool isq = blk >= 2;
  const int b0 = (isq? blk-2 : blk) * 16;
  const unsigned short* W  = isq? whh_q : whh_c;
  const unsigned short* GI = isq? gi_q  : gi_c;
  const float* bhh = isq? bhh_q : bhh_c;
  const float* h0  = isq? h0_q  : h0_c;
  const int steps  = isq? 32 : 1024;

  const int tid = threadIdx.x;
  const int lane = tid & 63, wave = tid >> 6;
  const int cl = lane & 15, q4 = lane >> 4;

  // B-fragments: [gate][subtile][kfrag], col base = g*256 + wave*32 + s*16
  bf16x8 Bf[3][2][8];
  #pragma unroll
  for(int g=0; g<3; g++)
    #pragma unroll
    for(int s=0; s<2; s++){
      const unsigned short* wrow = W + (size_t)(g*256 + wave*32 + s*16 + cl)*256;
      #pragma unroll
      for(int kf=0; kf<8; kf++)
        Bf[g][s][kf] = *(const bf16x8*)(wrow + kf*32 + q4*8);
    }

  // per-lane biases for owned cols
  float bR[2], bZ[2], bN[2];
  #pragma unroll
  for(int s=0; s<2; s++){
    const int col = wave*32 + s*16 + cl;
    bR[s] = bhh[col]; bZ[s] = bhh[256+col]; bN[s] = bhh[512+col];
  }

  // h carried in registers: lane owns (row=q4*4+r, col=wave*32+s*16+cl)
  float hreg[2][4];
  #pragma unroll
  for(int s=0; s<2; s++){
    const int col = wave*32 + s*16 + cl;
    #pragma unroll
    for(int r=0; r<4; r++){
      const int row = q4*4 + r;
      float v = h0[(size_t)(b0+row)*256 + col];
      hreg[s][r] = v;
      h_bf[row*264 + col] = f2bf(v);
    }
  }
  __syncthreads();

  for(int t=0; t<steps; t++){
    // stage gi(t) into LDS: wave handles rows 2w, 2w+1; two 1KB wave-loads per row
    #pragma unroll
    for(int r2=0; r2<2; r2++){
      const int row = wave*2 + r2;
      const unsigned short* src = GI + ((size_t)(b0+row)*steps + t)*768;
      #pragma unroll
      for(int half=0; half<2; half++)
        glds16(src + half*512 + lane*8, &gi_s[row*1032 + half*512]);
    }

    // deferred c_out store of h(t-1): overlaps with MFMA phase
    if(!isq && t>0){
      #pragma unroll
      for(int s=0; s<2; s++){
        const int col = wave*32 + s*16 + cl;
        #pragma unroll
        for(int r=0; r<4; r++)
          c_out[((size_t)(b0+q4*4+r)*1024 + (t-1))*256 + col] = hreg[s][r];
      }
    }

    // phase A: gates = h @ W^T  (48 MFMAs/wave)
    f32x4 acc[3][2];
    #pragma unroll
    for(int g=0; g<3; g++)
      #pragma unroll
      for(int s=0; s<2; s++){ f32x4 z={0.f,0.f,0.f,0.f}; acc[g][s]=z; }
    #pragma unroll
    for(int kf=0; kf<8; kf++){
      bf16x8 a = *(const bf16x8*)&h_bf[cl*264 + kf*32 + q4*8];
      #pragma unroll
      for(int g=0; g<3; g++)
        #pragma unroll
        for(int s=0; s<2; s++)
          acc[g][s] = __builtin_amdgcn_mfma_f32_16x16x32_bf16(a, Bf[g][s][kf], acc[g][s], 0,0,0);
    }
    __syncthreads();   // h_bf reads done; gi_s landed (vmcnt drained by barrier)

    // phase B: in-register GRU update on owned elements
    #pragma unroll
    for(int s=0; s<2; s++){
      const int col = wave*32 + s*16 + cl;
      #pragma unroll
      for(int r=0; r<4; r++){
        const int row = q4*4 + r;
        float gir = bf2f(gi_s[row*1032 + col]);
        float giz = bf2f(gi_s[row*1032 + 256 + col]);
        float gin = bf2f(gi_s[row*1032 + 512 + col]);
        float rr = sigm_f(gir + acc[0][s][r] + bR[s]);
        float zz = sigm_f(giz + acc[1][s][r] + bZ[s]);
        float nn = tanh_f(gin + rr*(acc[2][s][r] + bN[s]));
        float x  = nn + zz*(hreg[s][r] - nn);
        hreg[s][r] = x;
        h_bf[row*264 + col] = f2bf(x);
      }
    }
    __syncthreads();   // h_bf ready for next step's phase A
  }

  // final stores from hreg
  #pragma unroll
  for(int s=0; s<2; s++){
    const int col = wave*32 + s*16 + cl;
    #pragma unroll
    for(int r=0; r<4; r++){
      const int row = q4*4 + r;
      if(!isq) c_out[((size_t)(b0+row)*1024 + (steps-1))*256 + col] = hreg[s][r];
      else     q_hT[(size_t)(b0+row)*256 + col] = hreg[s][r];
    }
  }
}

// ---------------- attention helpers ----------------
__global__ void k_gather(const float* __restrict__ c_out, const int* __restrict__ c_index,
                         float* __restrict__ c_sel, unsigned short* __restrict__ c_sel_bf){
  int row = blockIdx.x;                 // 0..4095 = b*128+s
  int b = row >> 7, s = row & 127;
  int idx = c_index[b*128 + s];
  float v = c_out[((size_t)b*1024 + idx)*256 + threadIdx.x];
  c_sel   [(size_t)row*256 + threadIdx.x] = v;
  c_sel_bf[(size_t)row*256 + threadIdx.x] = f2bf(v);
}

__global__ void k_feats(const float* __restrict__ c_sel, const float* __restrict__ cw,
                        const float* __restrict__ m_, const float* __restrict__ qh,
                        unsigned short* __restrict__ feats){
  int row = blockIdx.x, tid = threadIdx.x;
  int b = row >> 7;
  float cs  = c_sel[(size_t)row*256 + tid];
  float mj  = m_[b*256 + tid];
  float qj  = qh[b*256 + tid];
  float cwj = cw[(size_t)row*256 + tid];
  float dq = cwj*qj, dm = cwj*mj;
  #pragma unroll
  for(int o=32;o>0;o>>=1){ dq += __shfl_down(dq,o); dm += __shfl_down(dm,o); }
  __shared__ float rq[4], rm[4];
  int lane = tid&63, wave=tid>>6;
  if(lane==0){ rq[wave]=dq; rm[wave]=dm; }
  __syncthreads();
  unsigned short* fr = feats + (size_t)row*1824;
  fr[tid]      = f2bf(cs);
  fr[256+tid]  = f2bf(mj);
  fr[512+tid]  = f2bf(qj);
  fr[768+tid]  = f2bf(cs*qj);
  fr[1024+tid] = f2bf(cs*mj);
  fr[1280+tid] = f2bf(fabsf(cs-qj));
  fr[1536+tid] = f2bf(fabsf(cs-mj));
  if(tid==0){
    float DQ = rq[0]+rq[1]+rq[2]+rq[3];
    float DM = rm[0]+rm[1]+rm[2]+rm[3];
    fr[1792]=f2bf(DQ); fr[1793]=f2bf(DM);
  }
  if(tid<30) fr[1794+tid]=0;   // zero K-pad
}

__global__ void k_scores(const float* __restrict__ h1, const float* __restrict__ w2,
                         const float* __restrict__ b2, float* __restrict__ scores){
  int row = blockIdx.x*4 + (threadIdx.x>>6);
  int lane = threadIdx.x & 63;
  float v = 0.0f;
  if(lane < 100)    v += h1[(size_t)row*128 + lane]*w2[lane];
  if(lane+64 < 100) v += h1[(size_t)row*128 + lane+64]*w2[lane+64];
  #pragma unroll
  for(int o=32;o>0;o>>=1) v += __shfl_down(v,o);
  if(lane==0) scores[row] = v + b2[0];
}

__global__ void k_softmax_e(const float* __restrict__ scores, const int* __restrict__ len_c,
                            const float* __restrict__ c_sel, float* __restrict__ out_att,
                            float* __restrict__ e){
  __shared__ float red[256];
  __shared__ float p[128];
  int b = blockIdx.x, tid = threadIdx.x;
  int L = len_c[b];
  float s = -1e30f;
  if(tid<128 && tid<L) s = scores[b*128+tid];
  red[tid]=s; __syncthreads();
  for(int o=128;o>0;o>>=1){ if(tid<o) red[tid]=fmaxf(red[tid],red[tid+o]); __syncthreads(); }
  float mx = red[0]; __syncthreads();
  float ex = (tid<128 && tid<L)? __expf(s-mx) : 0.0f;
  red[tid]=ex; __syncthreads();
  for(int o=128;o>0;o>>=1){ if(tid<o) red[tid]+=red[tid+o]; __syncthreads(); }
  float inv = 1.0f/red[0];
  if(tid<128){ float pv = ex*inv; p[tid]=pv; out_att[b*128+tid]=pv; }
  __syncthreads();
  float acc = 0.0f;
  for(int si=0; si<128; si++) acc += p[si]*c_sel[((size_t)b*128+si)*256 + tid];
  e[b*256+tid] = acc;
}

// ---------------- small fp32 GRU cell (mem/ans updates), x = [x1 || x2] ----------------
__global__ void k_gru_cell(const float* __restrict__ x1, int len1,
                           const float* __restrict__ x2, int len2,
                           const float* __restrict__ hprev,
                           const float* __restrict__ wihT, const float* __restrict__ whhT,
                           const float* __restrict__ bih, const float* __restrict__ bhh,
                           float* __restrict__ hout){
  __shared__ float xs[2304];
  __shared__ float hs[256];
  int m = blockIdx.x, tid = threadIdx.x;
  int Kx = len1 + len2;
  for(int i=tid;i<len1;i+=256) xs[i] = x1[(size_t)m*len1 + i];
  for(int i=tid;i<len2;i+=256) xs[len1+i] = x2[(size_t)m*len2 + i];
  hs[tid] = hprev[m*256 + tid];
  __syncthreads();
  float ar=0, az=0, an=0;
  for(int k=0;k<Kx;k++){
    float xv = xs[k];
    const float* wr = wihT + (size_t)k*768;
    ar += xv*wr[tid]; az += xv*wr[256+tid]; an += xv*wr[512+tid];
  }
  float gr=0, gz=0, gn=0;
  for(int k=0;k<256;k++){
    float hv = hs[k];
    const float* wr = whhT + (size_t)k*768;
    gr += hv*wr[tid]; gz += hv*wr[256+tid]; gn += hv*wr[512+tid];
  }
  float rr = sigm_f(ar + bih[tid]     + gr + bhh[tid]);
  float zz = sigm_f(az + bih[256+tid] + gz + bhh[256+tid]);
  float nn = tanh_f(an + bih[512+tid] + rr*(gn + bhh[512+tid]));
  hout[m*256+tid] = (1.0f-zz)*nn + zz*hs[tid];
}

// ---------------- answer head ----------------
__global__ void k_logits(const float* __restrict__ msq, const float* __restrict__ out_wT,
                         const float* __restrict__ out_b, float* __restrict__ ylin){
  int i = blockIdx.x*256 + threadIdx.x;
  if(i >= 32*2000) return;
  int mrow = i/2000, n = i - mrow*2000;
  float acc = out_b[n];
  const float* mr = msq + mrow*256;
  for(int k=0;k<256;k++) acc += mr[k]*out_wT[(size_t)k*2000 + n];
  ylin[i] = acc;
}

__global__ void k_softmax_o(const float* __restrict__ x, float* __restrict__ y){
  __shared__ float red[256];
  int b = blockIdx.x, tid = threadIdx.x;
  const float* xr = x + (size_t)b*2000;
  float mx = -1e30f;
  for(int i=tid;i<2000;i+=256) mx = fmaxf(mx, xr[i]);
  red[tid]=mx; __syncthreads();
  for(int o=128;o>0;o>>=1){ if(tid<o) red[tid]=fmaxf(red[tid],red[tid+o]); __syncthreads(); }
  mx = red[0]; __syncthreads();
  float sum=0.0f;
  for(int i=tid;i<2000;i+=256) sum += __expf(xr[i]-mx);
  red[tid]=sum; __syncthreads();
  for(int o=128;o>0;o>>=1){ if(tid<o) red[tid]+=red[tid+o]; __syncthreads(); }
  float inv = 1.0f/red[0];
  for(int i=tid;i<2000;i+=256) y[(size_t)b*2000+i] = __expf(xr[i]-mx)*inv;
}

// ---------------- launch ----------------
extern "C" void kernel_launch(void* const* d_in, const int* in_sizes, int n_in,
                              void* d_out, int out_size, void* d_ws, size_t ws_size,
                              hipStream_t stream)
{
  const float* c        = (const float*)d_in[0];
  const float* q        = (const float*)d_in[1];
  const float* i_state  = (const float*)d_in[2];
  const float* q_state  = (const float*)d_in[3];
  const float* in_w_ih  = (const float*)d_in[4];
  const float* in_w_hh  = (const float*)d_in[5];
  const float* in_b_ih  = (const float*)d_in[6];
  const float* in_b_hh  = (const float*)d_in[7];
  const float* qe_w_ih  = (const float*)d_in[8];
  const float* qe_w_hh  = (const float*)d_in[9];
  const float* qe_b_ih  = (const float*)d_in[10];
  const float* qe_b_hh  = (const float*)d_in[11];
  const float* att_weight = (const float*)d_in[12];
  const float* att_w1   = (const float*)d_in[13];
  const float* att_b1   = (const float*)d_in[14];
  const float* att_w2   = (const float*)d_in[15];
  const float* att_b2   = (const float*)d_in[16];
  const float* mem_w_ih = (const float*)d_in[17];
  const float* mem_w_hh = (const float*)d_in[18];
  const float* mem_b_ih = (const float*)d_in[19];
  const float* mem_b_hh = (const float*)d_in[20];
  const float* out_w    = (const float*)d_in[21];
  const float* out_b    = (const float*)d_in[22];
  const float* ans_w_ih = (const float*)d_in[23];
  const float* ans_w_hh = (const float*)d_in[24];
  const float* ans_b_ih = (const float*)d_in[25];
  const float* ans_b_hh = (const float*)d_in[26];
  const int*   c_index  = (const int*)d_in[27];
  const int*   len_c    = (const int*)d_in[28];
  float* outp = (float*)d_out;   // [0,64000) y ; [64000,76288) att (3,32,128)

  char* wp = (char*)d_ws;
  auto take = [&](size_t nbytes)->char*{
    char* p = wp; wp += (nbytes + 255) & ~(size_t)255; return p;
  };
  unsigned short* c_bf      = (unsigned short*)take((size_t)32*1024*128*2);
  unsigned short* q_bf      = (unsigned short*)take((size_t)32*32*128*2);
  unsigned short* wih_in_bf = (unsigned short*)take(768*128*2);
  unsigned short* wih_qe_bf = (unsigned short*)take(768*128*2);
  unsigned short* whh_in_bf = (unsigned short*)take(768*256*2);
  unsigned short* whh_qe_bf = (unsigned short*)take(768*256*2);
  unsigned short* attwT_bf  = (unsigned short*)take(256*256*2);
  unsigned short* attw1_bf  = (unsigned short*)take(128*1824*2);
  float* b1pad              = (float*)take(128*4);
  float* out_wT             = (float*)take((size_t)256*2000*4);
  float* mem_wihT           = (float*)take(256*768*4);
  float* mem_whhT           = (float*)take(256*768*4);
  float* ans_wihT           = (float*)take((size_t)2256*768*4);
  float* ans_whhT           = (float*)take(256*768*4);
  unsigned short* gi_c_bf   = (unsigned short*)take((size_t)32768*768*2);
  unsigned short* gi_q_bf   = (unsigned short*)take((size_t)1024*768*2);
  float* c_out              = (float*)take((size_t)32*1024*256*4);
  float* q_hT               = (float*)take(32*256*4);
  float* c_sel              = (float*)take((size_t)4096*256*4);
  unsigned short* c_sel_bf  = (unsigned short*)take((size_t)4096*256*2);
  float* cw                 = (float*)take((size_t)4096*256*4);
  unsigned short* feats_bf  = (unsigned short*)take((size_t)4096*1824*2);
  float* h1                 = (float*)take((size_t)4096*128*4);
  float* scores             = (float*)take(4096*4);
  float* e_buf              = (float*)take(32*256*4);
  float* m_buf              = (float*)take(32*256*4);
  float* msq                = (float*)take(32*256*4);
  float* ylin               = (float*)take((size_t)32*2000*4);
  float* ybuf               = (float*)take((size_t)32*2000*4);

  // ---- prep / conversions ----
  k_f2bf<<<16384,256,0,stream>>>(c, c_bf, 32*1024*128);
  k_f2bf<<<512,256,0,stream>>>(q, q_bf, 32*32*128);
  k_f2bf<<<384,256,0,stream>>>(in_w_ih, wih_in_bf, 768*128);
  k_f2bf<<<384,256,0,stream>>>(qe_w_ih, wih_qe_bf, 768*128);
  k_f2bf<<<768,256,0,stream>>>(in_w_hh, whh_in_bf, 768*256);
  k_f2bf<<<768,256,0,stream>>>(qe_w_hh, whh_qe_bf, 768*256);
  k_attwT<<<256,256,0,stream>>>(att_weight, attwT_bf);
  k_attw1<<<912,256,0,stream>>>(att_w1, attw1_bf);
  k_b1pad<<<1,128,0,stream>>>(att_b1, b1pad);
  k_transpose<<<2000,256,0,stream>>>(out_w, out_wT, 2000, 256);
  k_transpose<<<768,256,0,stream>>>(mem_w_ih, mem_wihT, 768, 256);
  k_transpose<<<768,256,0,stream>>>(mem_w_hh, mem_whhT, 768, 256);
  k_transpose<<<6768,256,0,stream>>>(ans_w_ih, ans_wihT, 768, 2256);
  k_transpose<<<768,256,0,stream>>>(ans_w_hh, ans_whhT, 768, 256);

  // ---- time-parallel input projections: gi = x @ w_ih^T + b_ih  (bf16 out) ----
  k_gemm_bf16<<<dim3(512,12),256,0,stream>>>(c_bf, wih_in_bf, 128, in_b_ih, 0, nullptr, gi_c_bf, 768);
  k_gemm_bf16<<<dim3(16,12),256,0,stream>>>(q_bf, wih_qe_bf, 128, qe_b_ih, 0, nullptr, gi_q_bf, 768);

  // ---- sequential GRU recurrences (context 1024 steps + query 32 steps) ----
  k_gru_rec<<<4,512,0,stream>>>(whh_in_bf, whh_qe_bf, gi_c_bf, gi_q_bf,
                                in_b_hh, qe_b_hh, i_state, q_state, c_out, q_hT);

  // ---- attention setup ----
  k_gather<<<4096,256,0,stream>>>(c_out, c_index, c_sel, c_sel_bf);
  k_gemm_bf16<<<dim3(64,4),256,0,stream>>>(c_sel_bf, attwT_bf, 256, nullptr, 0, cw, nullptr, 256);
  k_copy<<<32,256,0,stream>>>(q_hT, m_buf, 32*256);

  // ---- 3 episodic memory iterations ----
  for(int it=0; it<3; it++){
    k_feats<<<4096,256,0,stream>>>(c_sel, cw, m_buf, q_hT, feats_bf);
    k_gemm_bf16<<<dim3(64,2),256,0,stream>>>(feats_bf, attw1_bf, 1824, b1pad, 1, h1, nullptr, 128);
    k_scores<<<1024,256,0,stream>>>(h1, att_w2, att_b2, scores);
    k_softmax_e<<<32,256,0,stream>>>(scores, len_c, c_sel, outp + 64000 + it*4096, e_buf);
    k_gru_cell<<<32,256,0,stream>>>(e_buf, 256, nullptr, 0, m_buf,
                                    mem_wihT, mem_whhT, mem_b_ih, mem_b_hh, m_buf);
  }

  // ---- answer module ----
  k_copy<<<32,256,0,stream>>>(m_buf, msq, 32*256);
  for(int it=0; it<2; it++){
    k_logits<<<250,256,0,stream>>>(msq, out_wT, out_b, ylin);
    k_softmax_o<<<32,256,0,stream>>>(ylin, ybuf);
    k_gru_cell<<<32,256,0,stream>>>(ybuf, 2000, q_hT, 256, msq,
                                    ans_wihT, ans_whhT, ans_b_ih, ans_b_hh, msq);
  }
  k_logits<<<250,256,0,stream>>>(msq, out_wT, out_b, ylin);
  k_softmax_o<<<32,256,0,stream>>>(ylin, outp);
}

// Round 4
// 3052.217 us; speedup vs baseline: 1.5849x; 1.1412x over previous
//
#include <hip/hip_runtime.h>
#include <cstdint>
#include <cstddef>

typedef short bf16x8 __attribute__((ext_vector_type(8)));
typedef float f32x4 __attribute__((ext_vector_type(4)));
typedef int   i32x4 __attribute__((ext_vector_type(4)));

#define DEV static __device__ __forceinline__

DEV unsigned short f2bf(float x){
  union{float f; unsigned int u;} v; v.f = x;
  unsigned int r = (v.u + 0x7FFFu + ((v.u>>16)&1u)) >> 16;
  return (unsigned short)r;
}
DEV float bf2f(unsigned short h){
  union{unsigned int u; float f;} v; v.u = ((unsigned int)h)<<16;
  return v.f;
}
// unpack bf16 half of a dword: hi=0 -> low u16, hi=1 -> high u16
DEV float bfsel(int dw, int hi){
  union{unsigned int u; float f;} v;
  v.u = hi ? ((unsigned int)dw & 0xFFFF0000u) : ((unsigned int)dw << 16);
  return v.f;
}
// fast gates: v_exp_f32 + v_rcp_f32
DEV float sigm_f(float x){ return __builtin_amdgcn_rcpf(1.0f + __expf(-x)); }
DEV float tanh_f(float x){ return 2.0f*__builtin_amdgcn_rcpf(1.0f + __expf(-2.0f*x)) - 1.0f; }

// ---------------- prep kernels ----------------
__global__ void k_f2bf(const float* __restrict__ src, unsigned short* __restrict__ dst, int n){
  int i = blockIdx.x*256 + threadIdx.x;
  if(i<n) dst[i] = f2bf(src[i]);
}

__global__ void k_transpose(const float* __restrict__ in, float* __restrict__ out, int R, int C){
  int i = blockIdx.x*256 + threadIdx.x;
  if(i < R*C){ int r = i/C, c = i - r*C; out[(size_t)c*R + r] = in[i]; }
}

__global__ void k_attw1(const float* __restrict__ w1, unsigned short* __restrict__ dst){
  int i = blockIdx.x*256 + threadIdx.x;  // 128*1824
  if(i < 128*1824){
    int r = i/1824, cc = i - r*1824;
    float v = (r<100 && cc<1794)? w1[r*1794 + cc] : 0.0f;
    dst[i] = f2bf(v);
  }
}

__global__ void k_attwT(const float* __restrict__ aw, unsigned short* __restrict__ dst){
  int i = blockIdx.x*256 + threadIdx.x;  // out[n*256+k] = aw[k*256+n]
  if(i<65536){ int n = i>>8, k = i&255; dst[i] = f2bf(aw[k*256 + n]); }
}

__global__ void k_b1pad(const float* __restrict__ b1, float* __restrict__ dst){
  int i = threadIdx.x; if(i<128) dst[i] = (i<100)? b1[i] : 0.0f;
}

__global__ void k_copy(const float* __restrict__ s, float* __restrict__ d, int n){
  int i = blockIdx.x*256+threadIdx.x; if(i<n) d[i]=s[i];
}

// ---------------- generic bf16 MFMA GEMM: C(M,N) = A(M,K) @ Bt(N,K)^T ----------------
__global__ __launch_bounds__(256) void k_gemm_bf16(
    const unsigned short* __restrict__ A, const unsigned short* __restrict__ Bt,
    int K, const float* __restrict__ bias, int act,
    float* __restrict__ outf, unsigned short* __restrict__ outbf, int ldc)
{
  int lane = threadIdx.x & 63, wave = threadIdx.x >> 6;
  int m_base = blockIdx.x*64 + (wave>>1)*32;
  int n_base = blockIdx.y*64 + (wave&1)*32;
  int cl = lane & 15, q4 = lane >> 4;
  f32x4 acc00={0.f,0.f,0.f,0.f}, acc01=acc00, acc10=acc00, acc11=acc00;
  const int kf_n = K >> 5;
  for(int kf=0; kf<kf_n; kf++){
    int ko = kf*32 + q4*8;
    bf16x8 a0 = *(const bf16x8*)(A + (size_t)(m_base+cl)*K + ko);
    bf16x8 a1 = *(const bf16x8*)(A + (size_t)(m_base+16+cl)*K + ko);
    bf16x8 b0 = *(const bf16x8*)(Bt + (size_t)(n_base+cl)*K + ko);
    bf16x8 b1 = *(const bf16x8*)(Bt + (size_t)(n_base+16+cl)*K + ko);
    acc00 = __builtin_amdgcn_mfma_f32_16x16x32_bf16(a0,b0,acc00,0,0,0);
    acc01 = __builtin_amdgcn_mfma_f32_16x16x32_bf16(a0,b1,acc01,0,0,0);
    acc10 = __builtin_amdgcn_mfma_f32_16x16x32_bf16(a1,b0,acc10,0,0,0);
    acc11 = __builtin_amdgcn_mfma_f32_16x16x32_bf16(a1,b1,acc11,0,0,0);
  }
  #pragma unroll
  for(int mt=0; mt<2; mt++){
    #pragma unroll
    for(int nt=0; nt<2; nt++){
      f32x4 av = (mt==0)? (nt==0?acc00:acc01) : (nt==0?acc10:acc11);
      int col = n_base + nt*16 + cl;
      float bv = bias? bias[col] : 0.0f;
      #pragma unroll
      for(int r=0;r<4;r++){
        int row = m_base + mt*16 + q4*4 + r;
        float v = av[r] + bv;
        if(act) v = tanh_f(v);
        if(outbf) outbf[(size_t)row*ldc + col] = f2bf(v);
        else      outf [(size_t)row*ldc + col] = v;
      }
    }
  }
}

// ---------------- gi GEMM with lane-packed scatter epilogue ----------------
// Computes gi = x @ w_ih^T + b_ih and scatters each recurrence-lane's 24 values
// contiguous: idx = ((((t*2 + blk)*8 + w)*64 + lane)*24 + g*8 + s*4 + r.
// A rows are b*steps + t (steps = 1<<ss). N = 768.
__global__ __launch_bounds__(256) void k_gemm_gi(
    const unsigned short* __restrict__ A, const unsigned short* __restrict__ Bt,
    const float* __restrict__ bias, unsigned short* __restrict__ gi_out, int ss)
{
  int lane = threadIdx.x & 63, wave = threadIdx.x >> 6;
  int m_base = blockIdx.x*64 + (wave>>1)*32;
  int n_base = blockIdx.y*64 + (wave&1)*32;
  int cl = lane & 15, q4 = lane >> 4;
  f32x4 acc00={0.f,0.f,0.f,0.f}, acc01=acc00, acc10=acc00, acc11=acc00;
  for(int kf=0; kf<4; kf++){   // K = 128
    int ko = kf*32 + q4*8;
    bf16x8 a0 = *(const bf16x8*)(A + (size_t)(m_base+cl)*128 + ko);
    bf16x8 a1 = *(const bf16x8*)(A + (size_t)(m_base+16+cl)*128 + ko);
    bf16x8 b0 = *(const bf16x8*)(Bt + (size_t)(n_base+cl)*128 + ko);
    bf16x8 b1 = *(const bf16x8*)(Bt + (size_t)(n_base+16+cl)*128 + ko);
    acc00 = __builtin_amdgcn_mfma_f32_16x16x32_bf16(a0,b0,acc00,0,0,0);
    acc01 = __builtin_amdgcn_mfma_f32_16x16x32_bf16(a0,b1,acc01,0,0,0);
    acc10 = __builtin_amdgcn_mfma_f32_16x16x32_bf16(a1,b0,acc10,0,0,0);
    acc11 = __builtin_amdgcn_mfma_f32_16x16x32_bf16(a1,b1,acc11,0,0,0);
  }
  const int tmask = (1<<ss) - 1;
  #pragma unroll
  for(int mt=0; mt<2; mt++){
    #pragma unroll
    for(int nt=0; nt<2; nt++){
      f32x4 av = (mt==0)? (nt==0?acc00:acc01) : (nt==0?acc10:acc11);
      int col = n_base + nt*16 + cl;
      float bv = bias[col];
      int g = col >> 8, rem = col & 255;
      int w = rem >> 5, s = (rem>>4)&1, cl2 = rem & 15;
      #pragma unroll
      for(int r=0;r<4;r++){
        int arow = m_base + mt*16 + q4*4 + r;
        int t = arow & tmask, b = arow >> ss;
        int blk = b >> 4, brow = b & 15;
        int lane2 = (brow>>2)*16 + cl2, rc = brow & 3;
        size_t idx = ((((size_t)t*2 + blk)*8 + w)*64 + lane2)*24 + g*8 + s*4 + rc;
        gi_out[idx] = f2bf(av[r] + bv);
      }
    }
  }
}

// ---------------- GRU recurrence ----------------
// 4 blocks (2 context, 2 query), 16 batch rows each, 8 waves.
// Gate-local tiling (wave w owns cols [32w,32w+32) of r/z/n); W register-resident.
// h double-buffered in LDS -> ONE __syncthreads per step.
// gi loaded per-lane as 3x dwordx4 from the lane-packed layout (issued at step top,
// consumed in phase B via data-dependent vmcnt; no barrier interaction).
__global__ __launch_bounds__(512,1) void k_gru_rec(
    const unsigned short* __restrict__ whh_c, const unsigned short* __restrict__ whh_q,
    const unsigned short* __restrict__ gi_c,  const unsigned short* __restrict__ gi_q,
    const float* __restrict__ bhh_c, const float* __restrict__ bhh_q,
    const float* __restrict__ h0_c,  const float* __restrict__ h0_q,
    float* __restrict__ c_out, float* __restrict__ q_hT)
{
  __shared__ unsigned short hb0[16*264];   // double-buffered h (row stride 264 u16)
  __shared__ unsigned short hb1[16*264];

  const int blk = blockIdx.x;
  const bool isq = blk >= 2;
  const int cls = isq? blk-2 : blk;        // block index within class (0/1)
  const int b0 = cls * 16;
  const unsigned short* W  = isq? whh_q : whh_c;
  const unsigned short* GI = isq? gi_q  : gi_c;
  const float* bhh = isq? bhh_q : bhh_c;
  const float* h0  = isq? h0_q  : h0_c;
  const int steps  = isq? 32 : 1024;

  const int tid = threadIdx.x;
  const int lane = tid & 63, wave = tid >> 6;
  const int cl = lane & 15, q4 = lane >> 4;

  // B-fragments: [gate][subtile][kfrag], col = g*256 + wave*32 + s*16 + cl
  bf16x8 Bf[3][2][8];
  #pragma unroll
  for(int g=0; g<3; g++)
    #pragma unroll
    for(int s=0; s<2; s++){
      const unsigned short* wrow = W + (size_t)(g*256 + wave*32 + s*16 + cl)*256;
      #pragma unroll
      for(int kf=0; kf<8; kf++)
        Bf[g][s][kf] = *(const bf16x8*)(wrow + kf*32 + q4*8);
    }

  // per-lane biases for owned cols
  float bR[2], bZ[2], bN[2];
  #pragma unroll
  for(int s=0; s<2; s++){
    const int col = wave*32 + s*16 + cl;
    bR[s] = bhh[col]; bZ[s] = bhh[256+col]; bN[s] = bhh[512+col];
  }

  // h in registers: lane owns (row=q4*4+r, col=wave*32+s*16+cl)
  float hreg[2][4];
  #pragma unroll
  for(int s=0; s<2; s++){
    const int col = wave*32 + s*16 + cl;
    #pragma unroll
    for(int r=0; r<4; r++){
      const int row = q4*4 + r;
      float v = h0[(size_t)(b0+row)*256 + col];
      hreg[s][r] = v;
      hb0[row*264 + col] = f2bf(v);
    }
  }
  __syncthreads();

  unsigned short* hb_rd = hb0;
  unsigned short* hb_wr = hb1;

  // per-lane gi base for this (blk, wave, lane)
  const unsigned short* gi_lane = GI + (((size_t)cls*8 + wave)*64 + lane)*24;
  const size_t gi_tstride = (size_t)2*8*64*24;   // per-t stride in u16

  for(int t=0; t<steps; t++){
    // gi(t): 3x dwordx4 (48 B contiguous per lane); consumed in phase B
    const unsigned short* gp = gi_lane + (size_t)t*gi_tstride;
    i32x4 G0 = *(const i32x4*)(gp);        // gate r : [s0r0..s0r3, s1r0..s1r3]
    i32x4 G1 = *(const i32x4*)(gp + 8);    // gate z
    i32x4 G2 = *(const i32x4*)(gp + 16);   // gate n

    // deferred c_out store of h(t-1): overlaps with MFMA phase
    if(!isq && t>0){
      #pragma unroll
      for(int s=0; s<2; s++){
        const int col = wave*32 + s*16 + cl;
        #pragma unroll
        for(int r=0; r<4; r++)
          c_out[((size_t)(b0+q4*4+r)*1024 + (t-1))*256 + col] = hreg[s][r];
      }
    }

    // phase A: gates = h @ W^T  (48 MFMAs/wave)
    f32x4 acc[3][2];
    #pragma unroll
    for(int g=0; g<3; g++)
      #pragma unroll
      for(int s=0; s<2; s++){ f32x4 z={0.f,0.f,0.f,0.f}; acc[g][s]=z; }
    #pragma unroll
    for(int kf=0; kf<8; kf++){
      bf16x8 a = *(const bf16x8*)&hb_rd[cl*264 + kf*32 + q4*8];
      #pragma unroll
      for(int g=0; g<3; g++)
        #pragma unroll
        for(int s=0; s<2; s++)
          acc[g][s] = __builtin_amdgcn_mfma_f32_16x16x32_bf16(a, Bf[g][s][kf], acc[g][s], 0,0,0);
    }

    // phase B: in-register GRU update (writes OTHER h buffer -> no barrier needed here)
    #pragma unroll
    for(int s=0; s<2; s++){
      const int col = wave*32 + s*16 + cl;
      #pragma unroll
      for(int r=0; r<4; r++){
        const int row = q4*4 + r;
        const int k = s*4 + r;
        float gir = bfsel(G0[k>>1], k&1);
        float giz = bfsel(G1[k>>1], k&1);
        float gin = bfsel(G2[k>>1], k&1);
        float rr = sigm_f(gir + acc[0][s][r] + bR[s]);
        float zz = sigm_f(giz + acc[1][s][r] + bZ[s]);
        float nn = tanh_f(gin + rr*(acc[2][s][r] + bN[s]));
        float x  = nn + zz*(hreg[s][r] - nn);
        hreg[s][r] = x;
        hb_wr[row*264 + col] = f2bf(x);
      }
    }
    __syncthreads();   // hb_wr complete -> next step's phase A may read it
    unsigned short* tmp = hb_rd; hb_rd = hb_wr; hb_wr = tmp;
  }

  // final stores from hreg
  #pragma unroll
  for(int s=0; s<2; s++){
    const int col = wave*32 + s*16 + cl;
    #pragma unroll
    for(int r=0; r<4; r++){
      const int row = q4*4 + r;
      if(!isq) c_out[((size_t)(b0+row)*1024 + (steps-1))*256 + col] = hreg[s][r];
      else     q_hT[(size_t)(b0+row)*256 + col] = hreg[s][r];
    }
  }
}

// ---------------- attention helpers ----------------
__global__ void k_gather(const float* __restrict__ c_out, const int* __restrict__ c_index,
                         float* __restrict__ c_sel, unsigned short* __restrict__ c_sel_bf){
  int row = blockIdx.x;                 // 0..4095 = b*128+s
  int b = row >> 7, s = row & 127;
  int idx = c_index[b*128 + s];
  float v = c_out[((size_t)b*1024 + idx)*256 + threadIdx.x];
  c_sel   [(size_t)row*256 + threadIdx.x] = v;
  c_sel_bf[(size_t)row*256 + threadIdx.x] = f2bf(v);
}

__global__ void k_feats(const float* __restrict__ c_sel, const float* __restrict__ cw,
                        const float* __restrict__ m_, const float* __restrict__ qh,
                        unsigned short* __restrict__ feats){
  int row = blockIdx.x, tid = threadIdx.x;
  int b = row >> 7;
  float cs  = c_sel[(size_t)row*256 + tid];
  float mj  = m_[b*256 + tid];
  float qj  = qh[b*256 + tid];
  float cwj = cw[(size_t)row*256 + tid];
  float dq = cwj*qj, dm = cwj*mj;
  #pragma unroll
  for(int o=32;o>0;o>>=1){ dq += __shfl_down(dq,o); dm += __shfl_down(dm,o); }
  __shared__ float rq[4], rm[4];
  int lane = tid&63, wave=tid>>6;
  if(lane==0){ rq[wave]=dq; rm[wave]=dm; }
  __syncthreads();
  unsigned short* fr = feats + (size_t)row*1824;
  fr[tid]      = f2bf(cs);
  fr[256+tid]  = f2bf(mj);
  fr[512+tid]  = f2bf(qj);
  fr[768+tid]  = f2bf(cs*qj);
  fr[1024+tid] = f2bf(cs*mj);
  fr[1280+tid] = f2bf(fabsf(cs-qj));
  fr[1536+tid] = f2bf(fabsf(cs-mj));
  if(tid==0){
    float DQ = rq[0]+rq[1]+rq[2]+rq[3];
    float DM = rm[0]+rm[1]+rm[2]+rm[3];
    fr[1792]=f2bf(DQ); fr[1793]=f2bf(DM);
  }
  if(tid<30) fr[1794+tid]=0;   // zero K-pad
}

__global__ void k_scores(const float* __restrict__ h1, const float* __restrict__ w2,
                         const float* __restrict__ b2, float* __restrict__ scores){
  int row = blockIdx.x*4 + (threadIdx.x>>6);
  int lane = threadIdx.x & 63;
  float v = 0.0f;
  if(lane < 100)    v += h1[(size_t)row*128 + lane]*w2[lane];
  if(lane+64 < 100) v += h1[(size_t)row*128 + lane+64]*w2[lane+64];
  #pragma unroll
  for(int o=32;o>0;o>>=1) v += __shfl_down(v,o);
  if(lane==0) scores[row] = v + b2[0];
}

__global__ void k_softmax_e(const float* __restrict__ scores, const int* __restrict__ len_c,
                            const float* __restrict__ c_sel, float* __restrict__ out_att,
                            float* __restrict__ e){
  __shared__ float red[256];
  __shared__ float p[128];
  int b = blockIdx.x, tid = threadIdx.x;
  int L = len_c[b];
  float s = -1e30f;
  if(tid<128 && tid<L) s = scores[b*128+tid];
  red[tid]=s; __syncthreads();
  for(int o=128;o>0;o>>=1){ if(tid<o) red[tid]=fmaxf(red[tid],red[tid+o]); __syncthreads(); }
  float mx = red[0]; __syncthreads();
  float ex = (tid<128 && tid<L)? __expf(s-mx) : 0.0f;
  red[tid]=ex; __syncthreads();
  for(int o=128;o>0;o>>=1){ if(tid<o) red[tid]+=red[tid+o]; __syncthreads(); }
  float inv = 1.0f/red[0];
  if(tid<128){ float pv = ex*inv; p[tid]=pv; out_att[b*128+tid]=pv; }
  __syncthreads();
  float acc = 0.0f;
  for(int si=0; si<128; si++) acc += p[si]*c_sel[((size_t)b*128+si)*256 + tid];
  e[b*256+tid] = acc;
}

// ---------------- small fp32 GRU cell (mem/ans updates), x = [x1 || x2] ----------------
__global__ void k_gru_cell(const float* __restrict__ x1, int len1,
                           const float* __restrict__ x2, int len2,
                           const float* __restrict__ hprev,
                           const float* __restrict__ wihT, const float* __restrict__ whhT,
                           const float* __restrict__ bih, const float* __restrict__ bhh,
                           float* __restrict__ hout){
  __shared__ float xs[2304];
  __shared__ float hs[256];
  int m = blockIdx.x, tid = threadIdx.x;
  int Kx = len1 + len2;
  for(int i=tid;i<len1;i+=256) xs[i] = x1[(size_t)m*len1 + i];
  for(int i=tid;i<len2;i+=256) xs[len1+i] = x2[(size_t)m*len2 + i];
  hs[tid] = hprev[m*256 + tid];
  __syncthreads();
  float ar=0, az=0, an=0;
  for(int k=0;k<Kx;k++){
    float xv = xs[k];
    const float* wr = wihT + (size_t)k*768;
    ar += xv*wr[tid]; az += xv*wr[256+tid]; an += xv*wr[512+tid];
  }
  float gr=0, gz=0, gn=0;
  for(int k=0;k<256;k++){
    float hv = hs[k];
    const float* wr = whhT + (size_t)k*768;
    gr += hv*wr[tid]; gz += hv*wr[256+tid]; gn += hv*wr[512+tid];
  }
  float rr = sigm_f(ar + bih[tid]     + gr + bhh[tid]);
  float zz = sigm_f(az + bih[256+tid] + gz + bhh[256+tid]);
  float nn = tanh_f(an + bih[512+tid] + rr*(gn + bhh[512+tid]));
  hout[m*256+tid] = (1.0f-zz)*nn + zz*hs[tid];
}

// ---------------- answer head ----------------
__global__ void k_logits(const float* __restrict__ msq, const float* __restrict__ out_wT,
                         const float* __restrict__ out_b, float* __restrict__ ylin){
  int i = blockIdx.x*256 + threadIdx.x;
  if(i >= 32*2000) return;
  int mrow = i/2000, n = i - mrow*2000;
  float acc = out_b[n];
  const float* mr = msq + mrow*256;
  for(int k=0;k<256;k++) acc += mr[k]*out_wT[(size_t)k*2000 + n];
  ylin[i] = acc;
}

__global__ void k_softmax_o(const float* __restrict__ x, float* __restrict__ y){
  __shared__ float red[256];
  int b = blockIdx.x, tid = threadIdx.x;
  const float* xr = x + (size_t)b*2000;
  float mx = -1e30f;
  for(int i=tid;i<2000;i+=256) mx = fmaxf(mx, xr[i]);
  red[tid]=mx; __syncthreads();
  for(int o=128;o>0;o>>=1){ if(tid<o) red[tid]=fmaxf(red[tid],red[tid+o]); __syncthreads(); }
  mx = red[0]; __syncthreads();
  float sum=0.0f;
  for(int i=tid;i<2000;i+=256) sum += __expf(xr[i]-mx);
  red[tid]=sum; __syncthreads();
  for(int o=128;o>0;o>>=1){ if(tid<o) red[tid]+=red[tid+o]; __syncthreads(); }
  float inv = 1.0f/red[0];
  for(int i=tid;i<2000;i+=256) y[(size_t)b*2000+i] = __expf(xr[i]-mx)*inv;
}

// ---------------- launch ----------------
extern "C" void kernel_launch(void* const* d_in, const int* in_sizes, int n_in,
                              void* d_out, int out_size, void* d_ws, size_t ws_size,
                              hipStream_t stream)
{
  const float* c        = (const float*)d_in[0];
  const float* q        = (const float*)d_in[1];
  const float* i_state  = (const float*)d_in[2];
  const float* q_state  = (const float*)d_in[3];
  const float* in_w_ih  = (const float*)d_in[4];
  const float* in_w_hh  = (const float*)d_in[5];
  const float* in_b_ih  = (const float*)d_in[6];
  const float* in_b_hh  = (const float*)d_in[7];
  const float* qe_w_ih  = (const float*)d_in[8];
  const float* qe_w_hh  = (const float*)d_in[9];
  const float* qe_b_ih  = (const float*)d_in[10];
  const float* qe_b_hh  = (const float*)d_in[11];
  const float* att_weight = (const float*)d_in[12];
  const float* att_w1   = (const float*)d_in[13];
  const float* att_b1   = (const float*)d_in[14];
  const float* att_w2   = (const float*)d_in[15];
  const float* att_b2   = (const float*)d_in[16];
  const float* mem_w_ih = (const float*)d_in[17];
  const float* mem_w_hh = (const float*)d_in[18];
  const float* mem_b_ih = (const float*)d_in[19];
  const float* mem_b_hh = (const float*)d_in[20];
  const float* out_w    = (const float*)d_in[21];
  const float* out_b    = (const float*)d_in[22];
  const float* ans_w_ih = (const float*)d_in[23];
  const float* ans_w_hh = (const float*)d_in[24];
  const float* ans_b_ih = (const float*)d_in[25];
  const float* ans_b_hh = (const float*)d_in[26];
  const int*   c_index  = (const int*)d_in[27];
  const int*   len_c    = (const int*)d_in[28];
  float* outp = (float*)d_out;   // [0,64000) y ; [64000,76288) att (3,32,128)

  char* wp = (char*)d_ws;
  auto take = [&](size_t nbytes)->char*{
    char* p = wp; wp += (nbytes + 255) & ~(size_t)255; return p;
  };
  unsigned short* c_bf      = (unsigned short*)take((size_t)32*1024*128*2);
  unsigned short* q_bf      = (unsigned short*)take((size_t)32*32*128*2);
  unsigned short* wih_in_bf = (unsigned short*)take(768*128*2);
  unsigned short* wih_qe_bf = (unsigned short*)take(768*128*2);
  unsigned short* whh_in_bf = (unsigned short*)take(768*256*2);
  unsigned short* whh_qe_bf = (unsigned short*)take(768*256*2);
  unsigned short* attwT_bf  = (unsigned short*)take(256*256*2);
  unsigned short* attw1_bf  = (unsigned short*)take(128*1824*2);
  float* b1pad              = (float*)take(128*4);
  float* out_wT             = (float*)take((size_t)256*2000*4);
  float* mem_wihT           = (float*)take(256*768*4);
  float* mem_whhT           = (float*)take(256*768*4);
  float* ans_wihT           = (float*)take((size_t)2256*768*4);
  float* ans_whhT           = (float*)take(256*768*4);
  unsigned short* gi_c_bf   = (unsigned short*)take((size_t)32768*768*2);  // lane-packed
  unsigned short* gi_q_bf   = (unsigned short*)take((size_t)1024*768*2);   // lane-packed
  float* c_out              = (float*)take((size_t)32*1024*256*4);
  float* q_hT               = (float*)take(32*256*4);
  float* c_sel              = (float*)take((size_t)4096*256*4);
  unsigned short* c_sel_bf  = (unsigned short*)take((size_t)4096*256*2);
  float* cw                 = (float*)take((size_t)4096*256*4);
  unsigned short* feats_bf  = (unsigned short*)take((size_t)4096*1824*2);
  float* h1                 = (float*)take((size_t)4096*128*4);
  float* scores             = (float*)take(4096*4);
  float* e_buf              = (float*)take(32*256*4);
  float* m_buf              = (float*)take(32*256*4);
  float* msq                = (float*)take(32*256*4);
  float* ylin               = (float*)take((size_t)32*2000*4);
  float* ybuf               = (float*)take((size_t)32*2000*4);

  // ---- prep / conversions ----
  k_f2bf<<<16384,256,0,stream>>>(c, c_bf, 32*1024*128);
  k_f2bf<<<512,256,0,stream>>>(q, q_bf, 32*32*128);
  k_f2bf<<<384,256,0,stream>>>(in_w_ih, wih_in_bf, 768*128);
  k_f2bf<<<384,256,0,stream>>>(qe_w_ih, wih_qe_bf, 768*128);
  k_f2bf<<<768,256,0,stream>>>(in_w_hh, whh_in_bf, 768*256);
  k_f2bf<<<768,256,0,stream>>>(qe_w_hh, whh_qe_bf, 768*256);
  k_attwT<<<256,256,0,stream>>>(att_weight, attwT_bf);
  k_attw1<<<912,256,0,stream>>>(att_w1, attw1_bf);
  k_b1pad<<<1,128,0,stream>>>(att_b1, b1pad);
  k_transpose<<<2000,256,0,stream>>>(out_w, out_wT, 2000, 256);
  k_transpose<<<768,256,0,stream>>>(mem_w_ih, mem_wihT, 768, 256);
  k_transpose<<<768,256,0,stream>>>(mem_w_hh, mem_whhT, 768, 256);
  k_transpose<<<6768,256,0,stream>>>(ans_w_ih, ans_wihT, 768, 2256);
  k_transpose<<<768,256,0,stream>>>(ans_w_hh, ans_whhT, 768, 256);

  // ---- time-parallel input projections with lane-packed scatter ----
  k_gemm_gi<<<dim3(512,12),256,0,stream>>>(c_bf, wih_in_bf, in_b_ih, gi_c_bf, 10);
  k_gemm_gi<<<dim3(16,12),256,0,stream>>>(q_bf, wih_qe_bf, qe_b_ih, gi_q_bf, 5);

  // ---- sequential GRU recurrences (context 1024 steps + query 32 steps) ----
  k_gru_rec<<<4,512,0,stream>>>(whh_in_bf, whh_qe_bf, gi_c_bf, gi_q_bf,
                                in_b_hh, qe_b_hh, i_state, q_state, c_out, q_hT);

  // ---- attention setup ----
  k_gather<<<4096,256,0,stream>>>(c_out, c_index, c_sel, c_sel_bf);
  k_gemm_bf16<<<dim3(64,4),256,0,stream>>>(c_sel_bf, attwT_bf, 256, nullptr, 0, cw, nullptr, 256);
  k_copy<<<32,256,0,stream>>>(q_hT, m_buf, 32*256);

  // ---- 3 episodic memory iterations ----
  for(int it=0; it<3; it++){
    k_feats<<<4096,256,0,stream>>>(c_sel, cw, m_buf, q_hT, feats_bf);
    k_gemm_bf16<<<dim3(64,2),256,0,stream>>>(feats_bf, attw1_bf, 1824, b1pad, 1, h1, nullptr, 128);
    k_scores<<<1024,256,0,stream>>>(h1, att_w2, att_b2, scores);
    k_softmax_e<<<32,256,0,stream>>>(scores, len_c, c_sel, outp + 64000 + it*4096, e_buf);
    k_gru_cell<<<32,256,0,stream>>>(e_buf, 256, nullptr, 0, m_buf,
                                    mem_wihT, mem_whhT, mem_b_ih, mem_b_hh, m_buf);
  }

  // ---- answer module ----
  k_copy<<<32,256,0,stream>>>(m_buf, msq, 32*256);
  for(int it=0; it<2; it++){
    k_logits<<<250,256,0,stream>>>(msq, out_wT, out_b, ylin);
    k_softmax_o<<<32,256,0,stream>>>(ylin, ybuf);
    k_gru_cell<<<32,256,0,stream>>>(ybuf, 2000, q_hT, 256, msq,
                                    ans_wihT, ans_whhT, ans_b_ih, ans_b_hh, msq);
  }
  k_logits<<<250,256,0,stream>>>(msq, out_wT, out_b, ylin);
  k_softmax_o<<<32,256,0,stream>>>(ylin, outp);
}